// Round 9
// baseline (456.044 us; speedup 1.0000x reference)
//
#include <hip/hip_runtime.h>
#include <hip/hip_bf16.h>

// GCN over Block-CSR adjacency. ALL I/O BUFFERS ARE FLOAT32 (reference dtypes).
// Compute: bf16 MFMA, fp32 accumulate; intermediates stored bf16.
//
// Round 15: row-local fusion with BIT-IDENTICAL champion arithmetic.
// R14's fused kernel failed at absmax 0.021-0.023 (threshold 0.0216): it changed
// the rounding chain (swapped MFMA + reordered LN reduction) and structure at
// once; different rounding realizations move max-error 2-4x. Fix: keep the
// fusion (R14 measured 432us vs R13 445.7), but every arithmetic path is a
// verbatim copy of a passing kernel:
//  - spmm+LN: champion spmm_ln token-for-token (mfma(afr,bfr), tree reduce,
//    S/SS exchange, (bf16)y) — h-write goes to LDS HL[2][16][264] not HBM.
//  - dense: champion gemm_bt inner loop verbatim (A=h frags, B=WT bf16 16B
//    frags, k-chained) reading h from LDS; writes zbt layout byte-identically.
//  - W1/W2 pre-transposed f32->bf16 on device (champion transpose_all, merged
//    into the gemm0 dispatch as 320 extra WGs; w1t/w2t in d_out scratch,
//    consumed before spmm_out overwrites d_out — champion-proven lifetime).
//  - gemm0 = R13 gemm_lds (proven); spmm_out = champion verbatim.
// => every computed value bit-equals champion => absmax must be EXACTLY
// 0.005859375. 4 dispatches (was 6): gemm0+prep -> fused1 -> fused2 -> spmm_out.
//
// ws (128 MiB): zbt0@[64,128) -> zbt1@[0,64) -> zbt2@[64,80) (zbt0 dead).
// d_out: w1t/w2t scratch (160 KB) until fused2 completes; then spmm_out output.

typedef __bf16 bf16;
typedef bf16 bf16x8 __attribute__((ext_vector_type(8)));
typedef bf16 bf16x4 __attribute__((ext_vector_type(4)));
typedef float f32x4 __attribute__((ext_vector_type(4)));

#define N_NODES 131072
#define BRQ 8192      // block rows (= N/16)
#define KNZ 8         // nonzero blocks per block row
#define IN_F 128
#define HID 256
#define NCLS 64

static __device__ __forceinline__ f32x4 mfma16(bf16x8 a, bf16x8 b, f32x4 c) {
  return __builtin_amdgcn_mfma_f32_16x16x32_bf16(a, b, c, 0, 0, 0);
}

static __device__ __forceinline__ bf16x8 load8(const bf16* p) {
  return *(const bf16x8*)p;
}
static __device__ __forceinline__ bf16x8 cvt8(f32x4 a0, f32x4 a1) {
  bf16x8 r;
  r[0] = (bf16)a0[0]; r[1] = (bf16)a0[1]; r[2] = (bf16)a0[2]; r[3] = (bf16)a0[3];
  r[4] = (bf16)a1[0]; r[5] = (bf16)a1[1]; r[6] = (bf16)a1[2]; r[7] = (bf16)a1[3];
  return r;
}
static __device__ __forceinline__ bf16x8 load8(const float* p) {
  f32x4 a0 = *(const f32x4*)p;
  f32x4 a1 = *(const f32x4*)(p + 4);
  return cvt8(a0, a1);
}

// ---------------- dispatch 1: gemm0 (R13 gemm_lds, proven) + W1/W2 transpose -----
// blocks [0,1024): zbt0 = features @ W0 (LDS-staged W, high occupancy).
// blocks [1024,1344): w1t/w2t = bf16 transpose of W1/W2 (81920 elems total).
__global__ __launch_bounds__(256, 4) void gemm0_prep(
    const float* __restrict__ X, const float* __restrict__ W0,
    bf16* __restrict__ Zbt, const float* __restrict__ W1,
    const float* __restrict__ W2, bf16* __restrict__ w1t,
    bf16* __restrict__ w2t) {
  constexpr int KIN = IN_F, FOUT = HID, GRID = 1024;
  constexpr int CG  = FOUT / 64;
  constexpr int KS  = KIN / 32;
  constexpr int WGR = GRID / CG;
  constexpr int RTS = WGR * 4;
  constexpr int NT  = BRQ / RTS;
  constexpr int LDW = KIN + 8;

  __shared__ bf16 WL[64 * LDW];
  const int tid = threadIdx.x;

  if (blockIdx.x >= GRID) {
    int idx = (blockIdx.x - GRID) * 256 + tid;
    if (idx < HID * HID) {
      int r = idx >> 8, c = idx & 255;                 // W1: 256 x 256
      w1t[c * HID + r] = (bf16)W1[idx];
    } else {
      int j = idx - HID * HID;                         // W2: 256 x 64
      int r = j >> 6, c = j & 63;
      w2t[c * HID + r] = (bf16)W2[j];
    }
    return;
  }

  const int wave = tid >> 6;
  const int lane = tid & 63;
  const int l15  = lane & 15;
  const int quad = lane >> 4;
  const int cg   = blockIdx.x % CG;
  const int rg   = blockIdx.x / CG;
  const int rt0  = rg * 4 + wave;

  for (int e = tid; e < 64 * KIN; e += 256) {
    int c = e & 63, k = e >> 6;
    WL[c * LDW + k] = (bf16)W0[(long)k * FOUT + cg * 64 + c];
  }

  const float* __restrict__ xbase = X + (long)l15 * KIN + quad * 8;

  bf16x8 aw[2][KS];
#pragma unroll
  for (int k = 0; k < KS; ++k)
    aw[0][k] = load8(xbase + (long)rt0 * (16 * KIN) + k * 32);

  __syncthreads();

#pragma unroll
  for (int it = 0; it < NT; ++it) {
    const int rt = rt0 + it * RTS;
    if (it + 1 < NT) {
      const long xoff = (long)(rt + RTS) * (16 * KIN);
#pragma unroll
      for (int k = 0; k < KS; ++k)
        aw[(it + 1) & 1][k] = load8(xbase + xoff + k * 32);
    }
    f32x4 acc[4] = {};
    unsigned lo = 0;
#pragma unroll
    for (int k = 0; k < KS; ++k) {
      asm volatile("" : "+v"(lo));   // block LICM re-hoist of W frags (R13-proven)
#pragma unroll
      for (int t = 0; t < 4; ++t) {
        bf16x8 wf = *(const bf16x8*)(WL + lo + (t * 16 + l15) * LDW + k * 32 + quad * 8);
        acc[t] = mfma16(aw[it & 1][k], wf, acc[t]);
      }
    }
#pragma unroll
    for (int t = 0; t < 4; ++t) {
      int col = cg * 64 + t * 16 + l15;
      bf16x4 v;
#pragma unroll
      for (int i = 0; i < 4; ++i) v[i] = (bf16)acc[t][i];
      *(bf16x4*)(Zbt + ((long)rt * FOUT + col) * 16 + quad * 4) = v;
    }
  }
}

// ---------------- FUSED: champion spmm_ln (verbatim) -> h in LDS -> champion -----
// gemm_bt dense (verbatim, A from LDS). 4 waves = 2 block-rows, b = blk*2+pair.
template<int F_OUT>
__global__ __launch_bounds__(256) void spmm_ln_gemm(
    const float* __restrict__ Abv, const int* __restrict__ Abc,
    const bf16*  __restrict__ Zbt, const float* __restrict__ bias,
    const float* __restrict__ gamma, const float* __restrict__ beta,
    const bf16*  __restrict__ WT,   // [F_OUT][256] bf16 (pre-transposed)
    bf16* __restrict__ Zout) {      // [BRQ][F_OUT][16]
  constexpr int TD  = F_OUT / 32;   // dense col-frags per wave (wave covers F_OUT/2)
  constexpr int LHW = HID + 8;      // h row stride in LDS

  const int wave = threadIdx.x >> 6;
  const int lane = threadIdx.x & 63;
  const int l15  = lane & 15;
  const int quad = lane >> 4;
  const int b    = blockIdx.x * 2 + (wave >> 1);
  const int ch   = wave & 1;               // column half
  const int pair = wave >> 1;

  __shared__ bf16  HL[2][16 * LHW];
  __shared__ float S[4][16], SS[4][16];

  // ======== champion spmm_ln, verbatim ========
  const int*   bc    = Abc + b * KNZ;
  const int    cst   = (quad & 1) * 8;
  const int    half  = quad >> 1;
  const float* abase = Abv + (long)b * (KNZ * 256) + l15 * 16 + cst;

  bf16x8 afr[4];
  long   zb[4];
#pragma unroll
  for (int kp = 0; kp < 4; ++kp) {
    int blk = 2 * kp + half;
    afr[kp] = load8(abase + blk * 256);
    zb[kp]  = (long)bc[blk] * (HID * 16) + cst;
  }
  bf16x8 bfr[4][8];
#pragma unroll
  for (int kp = 0; kp < 4; ++kp)
#pragma unroll
    for (int t = 0; t < 8; ++t) {
      int f = ch * 128 + t * 16 + l15;
      bfr[kp][t] = *(const bf16x8*)(Zbt + zb[kp] + f * 16);
    }

  f32x4 acc[8] = {};
#pragma unroll
  for (int kp = 0; kp < 4; ++kp)
#pragma unroll
    for (int t = 0; t < 8; ++t)
      acc[t] = mfma16(afr[kp], bfr[kp][t], acc[t]);

  float gv[8], bv[8];
#pragma unroll
  for (int t = 0; t < 8; ++t) {
    int f = ch * 128 + t * 16 + l15;
    gv[t] = gamma[f];
    bv[t] = beta[f];
  }
  float ps[4] = {0.f, 0.f, 0.f, 0.f}, pss[4] = {0.f, 0.f, 0.f, 0.f};
#pragma unroll
  for (int t = 0; t < 8; ++t) {
    float bi = bias[ch * 128 + t * 16 + l15];
#pragma unroll
    for (int i = 0; i < 4; ++i) {
      float v = acc[t][i] + bi;
      v = v > 0.f ? v : 0.f;
      acc[t][i] = v;
      ps[i] += v;
      pss[i] += v * v;
    }
  }
#pragma unroll
  for (int m = 1; m < 16; m <<= 1) {
#pragma unroll
    for (int i = 0; i < 4; ++i) {
      ps[i]  += __shfl_xor(ps[i], m, 64);
      pss[i] += __shfl_xor(pss[i], m, 64);
    }
  }
  if (l15 == 0) {
#pragma unroll
    for (int i = 0; i < 4; ++i) {
      S[wave][quad * 4 + i]  = ps[i];
      SS[wave][quad * 4 + i] = pss[i];
    }
  }
  __syncthreads();
#pragma unroll
  for (int i = 0; i < 4; ++i) {
    int r = quad * 4 + i;
    float s    = S[wave][r] + S[wave ^ 1][r];
    float ss   = SS[wave][r] + SS[wave ^ 1][r];
    float mu   = s * (1.f / 256.f);
    float var  = ss * (1.f / 256.f) - mu * mu;
    float rstd = rsqrtf(var + 1e-5f);
    bf16* hrow = &HL[pair][r * LHW];           // <- ONLY change: LDS, not HBM
#pragma unroll
    for (int t = 0; t < 8; ++t) {
      int f = ch * 128 + t * 16 + l15;
      float y = (acc[t][i] - mu) * rstd * gv[t] + bv[t];
      hrow[f] = (bf16)y;
    }
  }
  __syncthreads();

  // ======== champion gemm_bt inner loop, verbatim (A = h from LDS) ========
  // wave covers cols [ch*(F_OUT/2), +F_OUT/2) of block-row rb = blk*2 + pair.
  const long  rb    = blockIdx.x * 2 + pair;
  const bf16* wbase = WT + (long)(ch * (F_OUT / 2) + l15) * HID + quad * 8;

  f32x4 dacc[TD] = {};
#pragma unroll
  for (int k = 0; k < 8; ++k) {
    bf16x8 ha = *(const bf16x8*)&HL[pair][l15 * LHW + k * 32 + quad * 8];
#pragma unroll
    for (int t = 0; t < TD; ++t) {
      bf16x8 wf = *(const bf16x8*)(wbase + t * (16 * HID) + k * 32);
      dacc[t] = mfma16(ha, wf, dacc[t]);
    }
  }
#pragma unroll
  for (int t = 0; t < TD; ++t) {
    int col = ch * (F_OUT / 2) + t * 16 + l15;
    bf16x4 v;
#pragma unroll
    for (int i = 0; i < 4; ++i) v[i] = (bf16)dacc[t][i];
    *(bf16x4*)(Zout + (rb * F_OUT + col) * 16 + quad * 4) = v;
  }
}

// ---------------- final SpMM + bias (F = NCLS = 64), f32 out — CHAMPION ----------
__global__ __launch_bounds__(256) void spmm_out(const float* __restrict__ Abv,
                                                const int*   __restrict__ Abc,
                                                const bf16*  __restrict__ Zbt,  // [BRQ,64,16]
                                                const float* __restrict__ bias, // [64]
                                                float* __restrict__ out) {      // [N,64] f32
  const int wave = threadIdx.x >> 6;
  const int b    = blockIdx.x * 4 + wave;   // one block-row per wave
  const int lane = threadIdx.x & 63;
  const int l15  = lane & 15;
  const int quad = lane >> 4;

  const int*   bc    = Abc + b * KNZ;
  const int    cst   = (quad & 1) * 8;
  const int    half  = quad >> 1;
  const float* abase = Abv + (long)b * (KNZ * 256) + l15 * 16 + cst;

  bf16x8 afr[4];
  long   zb[4];
#pragma unroll
  for (int kp = 0; kp < 4; ++kp) {
    int blk = 2 * kp + half;
    afr[kp] = load8(abase + blk * 256);
    zb[kp]  = (long)bc[blk] * (NCLS * 16) + cst;
  }
  bf16x8 bfr[4][4];
#pragma unroll
  for (int kp = 0; kp < 4; ++kp)
#pragma unroll
    for (int t = 0; t < 4; ++t) {
      int f = t * 16 + l15;
      bfr[kp][t] = *(const bf16x8*)(Zbt + zb[kp] + f * 16);
    }

  f32x4 acc[4] = {};
#pragma unroll
  for (int kp = 0; kp < 4; ++kp)
#pragma unroll
    for (int t = 0; t < 4; ++t)
      acc[t] = mfma16(afr[kp], bfr[kp][t], acc[t]);

#pragma unroll
  for (int t = 0; t < 4; ++t) {
    int f = t * 16 + l15;
    float bi = bias[f];
#pragma unroll
    for (int i = 0; i < 4; ++i) {
      out[(long)(b * 16 + quad * 4 + i) * NCLS + f] = acc[t][i] + bi;
    }
  }
}

extern "C" void kernel_launch(void* const* d_in, const int* in_sizes, int n_in,
                              void* d_out, int out_size, void* d_ws, size_t ws_size,
                              hipStream_t stream) {
  const float* features = (const float*)d_in[0];
  const float* bvals    = (const float*)d_in[1];
  const float* W0       = (const float*)d_in[2];
  const float* b0v      = (const float*)d_in[3];
  const float* W1       = (const float*)d_in[4];
  const float* b1v      = (const float*)d_in[5];
  const float* W2       = (const float*)d_in[6];
  const float* b2v      = (const float*)d_in[7];
  const float* g0       = (const float*)d_in[8];
  const float* beta0    = (const float*)d_in[9];
  const float* g1       = (const float*)d_in[10];
  const float* beta1    = (const float*)d_in[11];
  const int*   bcols    = (const int*)d_in[12];
  float* outp = (float*)d_out;

  // ws (128 MiB), disjoint lifetimes:
  char* ws = (char*)d_ws;
  bf16* zbt0 = (bf16*)(ws + (64L << 20));    // [64,128)  gemm0  -> fused1
  bf16* zbt1 = (bf16*)ws;                    // [0,64)    fused1 -> fused2
  bf16* zbt2 = (bf16*)(ws + (64L << 20));    // [64,80)   fused2 -> spmm_out (zbt0 dead)

  // transposed bf16 weights in d_out scratch (160 KB); all reads complete before
  // spmm_out overwrites d_out (stream order) — champion-proven lifetime.
  bf16* w1t = (bf16*)d_out;                  // [256][256]
  bf16* w2t = w1t + HID * HID;               // [64][256]

  // 1) zbt0 = features @ W0  (+ 320 WGs transposing W1/W2)
  gemm0_prep<<<dim3(1024 + 320), dim3(256), 0, stream>>>(
      features, W0, zbt0, W1, W2, w1t, w2t);
  // 2) zbt1 = LN(relu(A@zbt0 + b0)) @ W1   (h0 never leaves LDS)
  spmm_ln_gemm<HID><<<dim3(BRQ / 2), dim3(256), 0, stream>>>(
      bvals, bcols, zbt0, b0v, g0, beta0, w1t, zbt1);
  // 3) zbt2 = LN(relu(A@zbt1 + b1)) @ W2   (h1 never leaves LDS)
  spmm_ln_gemm<NCLS><<<dim3(BRQ / 2), dim3(256), 0, stream>>>(
      bvals, bcols, zbt1, b1v, g1, beta1, w2t, zbt2);
  // 4) out = A@zbt2 + b2
  spmm_out<<<dim3(BRQ / 4), dim3(256), 0, stream>>>(bvals, bcols, zbt2, b2v, outp);
}